// Round 4
// baseline (511.673 us; speedup 1.0000x reference)
//
#include <hip/hip_runtime.h>

// Problem constants
#define BB 4
#define CC 32
#define LL 50176              // 224*224
#define KK2 25
#define CDTOT (BB * LL * KK2) // 5,017,600 floats in cd

typedef float float4u __attribute__((ext_vector_type(4), aligned(4)));
typedef float float4a __attribute__((ext_vector_type(4), aligned(16)));

template <int N> struct IC { static constexpr int v = N; };

// Derivation (verified rounds 1-3): out[b,c2,l2] = in[b,c2,l2]*S, S = sum_k2 w*V,
//   V at flat addr = A0(r,k2) + ii + 1568*c2 (unclamped-linear in ii), where
//   l2 = rem0 + r + 800*ii, A0 = c*LL + 224*dy + dx + e, e = 62*k2 + (576*k2+rem)/800,
//   (c,s) from (576*k2+rem)%800, dy=s/5-2, dx=s%5-2.
//   w = xok ? cd[l2,k2]*cw + pos[k2]*pw : 0   (x-mask folded into weight table)
// Block: 16 consecutive rems x 64 ii x 8 channels. Lane owns (r, 4 consecutive ii)
//   -> gathers are dwordx4; stores (after LDS transpose) are full 64B lines.
// Weights in bf16 LDS table (k2 split in 2 phases -> LDS 40KB -> 4 blocks/CU; all
//   800 blocks co-resident). c2=0/31 y-boundary handled in a clamped scalar pass.

#define RSTR 884   // ushorts per r-row of weight table (>= 13*68, 8B-aligned rows)

__global__ __launch_bounds__(256, 4) void conv_local_kernel(
    const float* __restrict__ input,
    const float* __restrict__ cd,
    const float* __restrict__ colw,
    const float* __restrict__ posw,
    float* __restrict__ out)
{
    __shared__ ushort w_lds[16 * RSTR];   // 28288 B  [r][k2'*68 + ii]
    __shared__ int    A0_lds[400];        // 1600 B   [r*25 + k2]
    __shared__ int    xb_lds[400];        // 1600 B   packed xbase|dx|dy|ybase|c
    __shared__ float  sx[2][16 * 68];     // 8704 B   exchange, dbuf

    const int t    = threadIdx.x;
    const int lane = t & 63;
    const int w    = t >> 6;

    // XCD-pinned grid decode: 800 = 8 xcd * 100
    const int bx   = blockIdx.x;
    const int xcd  = bx & 7;
    const int b    = xcd >> 1;                    // batch pinned to XCD pair
    const int j    = (bx >> 3) * 2 + (xcd & 1);   // 0..199
    const int chunk = j & 3;                      // 8-channel chunk
    const int tile  = j >> 2;                     // 0..49
    const int rem0  = tile * 16;
    const int c2base = chunk * 8;
    const bool chunk0 = (chunk == 0);
    const bool chunk3 = (chunk == 3);

    const float cw = colw[0];
    const float pw = posw[0];
    const float* __restrict__ in_b  = input + b * (CC * LL);
    float* __restrict__       out_b = out   + b * (CC * LL);
    const int bcd = b * (LL * KK2);

    const float POS[KK2] = {8,5,4,5,8, 5,2,1,2,5, 4,1,0,1,4, 5,2,1,2,5, 8,5,4,5,8};

    // ---- stage 1: per-(r,k2) decode tables (400 entries) ----
    for (int d = t; d < 400; d += 256) {
        int r  = d / 25;
        int k2 = d - r * 25;
        int rem = rem0 + r;
        int t1 = 576 * k2 + rem;
        int q0 = t1 / 800;
        int rd = t1 - q0 * 800;
        int c  = rd / 25;
        int s  = rd - c * 25;
        int dy = s / 5 - 2;
        int dx = s % 5 - 2;
        int e  = 62 * k2 + q0;          // <= 1506
        int yb = e / 224;               // 0..6
        int xbv = e - yb * 224;
        A0_lds[d] = c * LL + 224 * dy + dx + e;
        xb_lds[d] = xbv | ((dx + 2) << 8) | ((dy + 2) << 11) | (yb << 14) | (c << 17);
    }
    __syncthreads();

    // main-mapping lane constants: r = 4*w + rs, ii = 4*g + sub
    const int rs  = lane >> 4;
    const int g   = lane & 15;
    const int r   = 4 * w + rs;
    const int ii0 = 4 * g;

    // stage-2 mapping: thread (ii, tq) fills rows r = 4*tq+rowl of its ii column
    const int iiS = t >> 2;
    const int tqS = t & 3;

    float4a acc[8];
    #pragma unroll
    for (int ch = 0; ch < 8; ++ch) acc[ch] = (float4a)(0.f);

    const int spch = chunk0 ? 0 : 7;    // special channel slot (if any)

    auto phase = [&](auto K0T, auto NKT) {
        constexpr int K0 = decltype(K0T)::v;
        constexpr int NK = decltype(NKT)::v;

        // ---- stage 2: fill bf16 weight table for k2 in [K0, K0+NK) ----
        #pragma unroll
        for (int rowl = 0; rowl < 4; ++rowl) {
            const int rr = 4 * tqS + rowl;
            const int l2 = rem0 + rr + 800 * iiS;
            int rowidx = bcd + l2 * 25 + K0;
            rowidx = min(rowidx, CDTOT - 16);       // OOB rows: safe garbage
            float cv[16];
            float4u q0v = *(const float4u*)&cd[rowidx + 0];
            float4u q1v = *(const float4u*)&cd[rowidx + 4];
            float4u q2v = *(const float4u*)&cd[rowidx + 8];
            cv[0]=q0v.x; cv[1]=q0v.y; cv[2]=q0v.z; cv[3]=q0v.w;
            cv[4]=q1v.x; cv[5]=q1v.y; cv[6]=q1v.z; cv[7]=q1v.w;
            cv[8]=q2v.x; cv[9]=q2v.y; cv[10]=q2v.z; cv[11]=q2v.w;
            if (NK == 13) cv[12] = cd[rowidx + 12];
            #pragma unroll
            for (int kk = 0; kk < NK; ++kk) {
                const int k2 = K0 + kk;
                const int xbp = xb_lds[rr * 25 + k2];
                int xbase = xbp & 255;
                int dxv   = ((xbp >> 8) & 7) - 2;
                int xst   = xbase + iiS;
                xst -= (xst >= 224) ? 224 : 0;
                bool xok  = (unsigned)(xst + dxv) < 224u;
                float wv  = xok ? fmaf(cv[kk], cw, POS[k2] * pw) : 0.0f;
                unsigned ub = __float_as_uint(wv);
                ub = ub + 0x7FFFu + ((ub >> 16) & 1u);    // RNE to bf16
                w_lds[rr * RSTR + kk * 68 + iiS] = (ushort)(ub >> 16);
            }
        }
        __syncthreads();

        // ---- main: k2-outer, channel-inner, x4 gathers ----
        #pragma unroll
        for (int kk = 0; kk < NK; ++kk) {
            const int A0v = A0_lds[r * 25 + K0 + kk];
            const int Ak  = A0v + ii0;
            const uint2 wp = *(const uint2*)&w_lds[r * RSTR + kk * 68 + ii0];
            float4a w4;
            w4.x = __uint_as_float(wp.x << 16);
            w4.y = __uint_as_float(wp.x & 0xFFFF0000u);
            w4.z = __uint_as_float(wp.y << 16);
            w4.w = __uint_as_float(wp.y & 0xFFFF0000u);
            #pragma unroll
            for (int ch = 0; ch < 8; ++ch) {
                if (ch == 0 && chunk0) continue;     // uniform skip (special)
                if (ch == 7 && chunk3) continue;
                const float* p = in_b + (c2base + ch) * 1568 + Ak;
                float4u v = *(const float4u*)p;
                acc[ch].x = fmaf(v.x, w4.x, acc[ch].x);
                acc[ch].y = fmaf(v.y, w4.y, acc[ch].y);
                acc[ch].z = fmaf(v.z, w4.z, acc[ch].z);
                acc[ch].w = fmaf(v.w, w4.w, acc[ch].w);
            }
        }

        // ---- special channels c2=0 / c2=31: clamped + y-masked scalar pass ----
        if (chunk0 | chunk3) {
            #pragma unroll
            for (int kk = 0; kk < NK; ++kk) {
                const int xbp = xb_lds[r * 25 + K0 + kk];
                const int xbase = xbp & 255;
                const int dxv   = ((xbp >> 8) & 7) - 2;
                const int dyv   = ((xbp >> 11) & 7) - 2;
                const int ybv   = (xbp >> 14) & 7;
                const int cc    = (xbp >> 17) & 31;
                const uint2 wp = *(const uint2*)&w_lds[r * RSTR + kk * 68 + ii0];
                float wa[4];
                wa[0] = __uint_as_float(wp.x << 16);
                wa[1] = __uint_as_float(wp.x & 0xFFFF0000u);
                wa[2] = __uint_as_float(wp.y << 16);
                wa[3] = __uint_as_float(wp.y & 0xFFFF0000u);
                float4a vv;
                #pragma unroll
                for (int s = 0; s < 4; ++s) {
                    const int iiX = ii0 + s;
                    int xst = xbase + iiX;
                    int carry = (xst >= 224) ? 1 : 0;
                    xst -= carry ? 224 : 0;
                    const int yy = ybv + carry + dyv;        // [-2, 9]
                    const int xm = xst + dxv;
                    const int xc = min(max(xm, 0), 223);
                    int ycl; bool ok;
                    if (chunk0) { ycl = max(yy, 0); ok = (yy >= 0); }
                    else        { ycl = 217 + min(yy, 6); ok = (yy <= 6); }
                    const float vl = in_b[cc * LL + ycl * 224 + xc];
                    float val = ok ? vl : 0.0f;
                    if (s == 0) vv.x = val * wa[0];
                    if (s == 1) vv.y = val * wa[1];
                    if (s == 2) vv.z = val * wa[2];
                    if (s == 3) vv.w = val * wa[3];
                }
                acc[spch] += vv;
            }
        }
        __syncthreads();   // before next phase overwrites w_lds
    };

    phase(IC<0>{}, IC<12>{});
    phase(IC<12>{}, IC<13>{});

    // ---- exchange + coalesced multiply/store (full 64B lines) ----
    const int iiB = t >> 2;
    const int rq  = t & 3;
    const int l2q = rem0 + 4 * rq + 800 * iiB;
    const bool okB = (l2q < LL);          // quads never straddle LL (mult of 4)
    const int l2c = okB ? l2q : 0;

    #pragma unroll 1
    for (int ch = 0; ch < 8; ++ch) {
        float* buf = sx[ch & 1];
        *(float4a*)&buf[r * 68 + ii0] = acc[ch];
        __syncthreads();
        float4a S;
        S.x = buf[(4 * rq + 0) * 68 + iiB];
        S.y = buf[(4 * rq + 1) * 68 + iiB];
        S.z = buf[(4 * rq + 2) * 68 + iiB];
        S.w = buf[(4 * rq + 3) * 68 + iiB];
        const int oidx = (c2base + ch) * LL + l2c;
        if (okB) {
            float4a iv = *(const float4a*)(in_b + oidx);
            float4a res = S * iv;
            __builtin_nontemporal_store(res, (float4a*)(out_b + oidx));
        }
        // no trailing barrier: dbuf; writes to this buf (ch+2) are behind
        // barrier(ch+1) which follows these reads
    }
}

extern "C" void kernel_launch(void* const* d_in, const int* in_sizes, int n_in,
                              void* d_out, int out_size, void* d_ws, size_t ws_size,
                              hipStream_t stream) {
    const float* input = (const float*)d_in[0];
    const float* cdist = (const float*)d_in[1];
    const float* cwp   = (const float*)d_in[2];
    const float* pwp   = (const float*)d_in[3];
    float* o = (float*)d_out;

    dim3 grid(800);    // 4 b x 4 chunks x 50 tiles, XCD-pinned in-kernel
    dim3 block(256);
    hipLaunchKernelGGL(conv_local_kernel, grid, block, 0, stream,
                       input, cdist, cwp, pwp, o);
}

// Round 5
// 270.743 us; speedup vs baseline: 1.8899x; 1.8899x over previous
//
#include <hip/hip_runtime.h>

// Problem constants
#define BB 4
#define CC 32
#define LL 50176              // 224*224
#define KK2 25
#define CDTOT (BB * LL * KK2) // 5,017,600 floats in cd

// out[b,c2,l2] = in[b,c2,l2] * sum_k2 Wt(b,l2,k2) * V(b,n),
//   n = c2*1254400 + k2*50176 + l2 ; decode l=n/800, c=(n%800)/25, s=n%25.
// Lanes stride l2 by 800 (l2 = rem + 800*ii):
//   (c,s,dy,dx) wave-uniform (scalar), gather addresses consecutive per lane.
// Gather addr = A(k2,ii) + 1568*c2 with A = c*LL + (ys+dy)*224 + xc.
// ROUND 5: A stored as BYTE offset AB = 4*(A+1568) (bias => non-negative),
//   loads go through uniform per-channel base bj = in_b + 4*1568*(jj-1)
//   -> compiler emits saddr-form global_load (no per-load 64-bit addr math).
// y-OOB only at c2==0 / c2==31 -> masked special iterations.
// Stores are PLAIN (nontemporal stores defeated L2 write-combining: 50->97MB).

__global__ __launch_bounds__(256) void conv_local_kernel(
    const float* __restrict__ input,
    const float* __restrict__ cd,
    const float* __restrict__ colw,
    const float* __restrict__ posw,
    float* __restrict__ out)
{
    __shared__ float smem[64 * 101 + 8];  // setup: cds[64][101]; main: sx dbuf 2*1040

    const int t    = threadIdx.x;
    const int lane = t & 63;
    const int w    = t >> 6;              // wave 0..3 -> rem = rem0 + w

    // XCD-locality swizzle (blocks assigned round-robin to 8 XCDs)
    const int bx   = blockIdx.x;          // 0..1599
    const int xcd  = bx & 7;
    const int slot = bx >> 3;             // 0..199
    const int b    = xcd >> 1;            // batch pinned to XCD pair
    const int j    = slot * 2 + (xcd & 1);// 0..399 within batch
    const int chunk  = j & 1;             // c2-chunk: [0,16) or [16,32)
    const int rem0   = (j >> 1) * 4;      // 0..796
    const int c2base = chunk * 16;

    const float cw = colw[0];
    const float pw = posw[0];
    const float* __restrict__ in_b  = input + b * (CC * LL);
    float* __restrict__       out_b = out   + b * (CC * LL);

    // ---- stage cd for this block's 256 l2 values, coalesced + nontemporal ----
    {
        const int cd_base = b * (LL * KK2);
        #pragma unroll
        for (int jld = 0; jld < 25; ++jld) {
            int flat = t + 256 * jld;            // [0, 6400)
            int ci   = flat / 100;               // ii 0..63
            int pos  = flat - ci * 100;          // (rem-rem0)*25 + k2
            int gidx = cd_base + (rem0 + 800 * ci) * KK2 + pos;
            gidx = min(gidx, CDTOT - 1);         // clamp OOB tail (values unused)
            smem[ci * 101 + pos] = __builtin_nontemporal_load(&cd[gidx]);
        }
    }
    __syncthreads();

    // ---- per-thread setup ----
    const int remU = __builtin_amdgcn_readfirstlane(rem0 + w);  // wave-uniform
    const int ii   = lane;

    unsigned AB[KK2];   // byte offset, biased by +1568 floats
    float    Wt[KK2];
    const float POS[KK2] = {8,5,4,5,8, 5,2,1,2,5, 4,1,0,1,4, 5,2,1,2,5, 8,5,4,5,8};

    #pragma unroll
    for (int k2 = 0; k2 < KK2; ++k2) {
        int t1 = 576 * k2 + remU;       // scalar...
        int q0 = t1 / 800;
        int r  = t1 - q0 * 800;
        int c  = r / 25;
        int s  = r - c * 25;
        int dy = s / 5 - 2;
        int dx = s % 5 - 2;
        int u  = 62 * k2 + q0 + ii;     // vector: +lane
        int ys = u / 224;               // [0,7]
        int xs = u - ys * 224;
        int xm = xs + dx;
        bool xok = (unsigned)xm < 224u;
        int xc = min(max(xm, 0), 223);
        float wgt = fmaf(smem[ii * 101 + w * 25 + k2], cw, POS[k2] * pw);
        Wt[k2] = xok ? wgt : 0.0f;      // x-mask folded into weight
        int A  = c * LL + (ys + dy) * 224 + xc + c2base * 1568;
        AB[k2] = (unsigned)(4 * (A + 1568));   // biased byte offset, >= 0
    }
    __syncthreads();   // smem reused as exchange buffer from here

    // mapping B (contiguous-l2) constants for coalesced multiply+store
    const int remB = t & 3;
    const int iiB  = t >> 2;
    const int l2B  = rem0 + remB + 800 * iiB;
    const bool okB = l2B < LL;
    const int idxB = min(l2B, LL - 1);

    // ---- main loop: 4 groups of 4 channels ----
    #pragma unroll 1
    for (int gg = 0; gg < 4; ++gg) {
        float acc[4];
        float iv[4];
        int   oidx[4];
        #pragma unroll
        for (int g = 0; g < 4; ++g) {
            oidx[g] = (c2base + gg * 4 + g) * LL + idxB;
            iv[g]   = in_b[oidx[g]];     // independent of gathers; overlaps
        }
        #pragma unroll
        for (int g = 0; g < 4; ++g) {
            const int jj = gg * 4 + g;
            const bool sp0  = (chunk == 0) && (jj == 0);    // c2 == 0
            const bool sp31 = (chunk == 1) && (jj == 15);   // c2 == 31
            float a = 0.0f;
            if (sp0 | sp31) {
                #pragma unroll
                for (int k2 = 0; k2 < KK2; ++k2) {
                    int t1 = 576 * k2 + remU;
                    int q0 = t1 / 800;
                    int r  = t1 - q0 * 800;
                    int c  = r / 25;
                    int s  = r - c * 25;
                    int dy = s / 5 - 2;
                    int dx = s % 5 - 2;
                    int u  = 62 * k2 + q0 + ii;
                    int ys = u / 224;
                    int xs = u - ys * 224;
                    int xc = min(max(xs + dx, 0), 223);
                    int yy = ys + dy;                     // [-2, 9]
                    int yb = sp0 ? max(yy, 0) : (217 + min(yy, 6));
                    bool ok = sp0 ? (yy >= 0) : (yy <= 6);
                    float v = in_b[c * LL + yb * 224 + xc];
                    a = fmaf(ok ? v : 0.0f, Wt[k2], a);
                }
            } else {
                // uniform per-channel base; divergent u32 byte offset -> saddr
                const char* bj = (const char*)in_b + 4 * 1568 * (jj - 1);
                #pragma unroll
                for (int k2 = 0; k2 < KK2; ++k2) {
                    float v = *(const float*)(bj + AB[k2]);
                    a = fmaf(v, Wt[k2], a);
                }
            }
            acc[g] = a;
        }

        // exchange S to mapping B; double-buffered (1040 floats each)
        float* sbuf = smem + (gg & 1) * 1040;
        #pragma unroll
        for (int g = 0; g < 4; ++g)
            sbuf[g * 260 + w * 65 + lane] = acc[g];
        __syncthreads();
        #pragma unroll
        for (int g = 0; g < 4; ++g) {
            float S = sbuf[g * 260 + remB * 65 + iiB];
            if (okB) out_b[oidx[g]] = S * iv[g];   // plain store: L2 combines lines
        }
        // no trailing barrier: dbuf; writes to this buf (gg+2) are behind
        // barrier(gg+1) which follows these reads
    }
}

extern "C" void kernel_launch(void* const* d_in, const int* in_sizes, int n_in,
                              void* d_out, int out_size, void* d_ws, size_t ws_size,
                              hipStream_t stream) {
    const float* input = (const float*)d_in[0];
    const float* cdist = (const float*)d_in[1];
    const float* cwp   = (const float*)d_in[2];
    const float* pwp   = (const float*)d_in[3];
    float* o = (float*)d_out;

    dim3 grid(1600);   // 4 b x 2 chunks x 200 rem0-tiles, XCD-pinned in-kernel
    dim3 block(256);
    hipLaunchKernelGGL(conv_local_kernel, grid, block, 0, stream,
                       input, cdist, cwp, pwp, o);
}

// Round 6
// 137.538 us; speedup vs baseline: 3.7202x; 1.9685x over previous
//
#include <hip/hip_runtime.h>

// Problem constants
#define BB 4
#define CC 32
#define LL 50176              // 224*224
#define KK2 25
#define CDTOT (BB * LL * KK2) // 5,017,600 floats in cd

// out[b,c2,l2] = in[b,c2,l2] * sum_k2 Wt(b,l2,k2) * V(b,n).
// Lanes stride l2 by 800 (l2 = rem + 800*ii, rem wave-uniform).
// KEY IDENTITY: ys*224 + xs = u  =>  unclamped gather addr
//     addr = A0(k2) + ii + 1568*c2,  A0 = c*LL + 224*dy + dx + e0  (WAVE-UNIFORM)
// x-OOB lanes read +-2 off (in-bounds within batch slab) but weight=0.
// => load is uniform_base[ii]: saddr form, 1 VALU + 1 load per MAC, A-table in SGPRs.
// Interior c2 in [1,30] always y-in-bounds; c2=0/31 via clamped special pass.
// Stores PLAIN (R5: nontemporal stores defeated write-combining 25->97MB).
// 8 channels per exchange group -> 200 loads in flight, 2 barriers.

__global__ __launch_bounds__(256) void conv_local_kernel(
    const float* __restrict__ input,
    const float* __restrict__ cd,
    const float* __restrict__ colw,
    const float* __restrict__ posw,
    float* __restrict__ out)
{
    __shared__ float smem[64 * 101 + 8];  // 6472 floats: cd staging, then 2x2560 exchange

    const int t    = threadIdx.x;
    const int lane = t & 63;
    const int w    = t >> 6;              // wave 0..3 -> rem = rem0 + w

    // XCD-locality swizzle (validated R3: FETCH 211->42MB)
    const int bx   = blockIdx.x;          // 0..1599
    const int xcd  = bx & 7;
    const int slot = bx >> 3;             // 0..199
    const int b    = xcd >> 1;            // batch pinned to XCD pair
    const int j    = slot * 2 + (xcd & 1);// 0..399 within batch
    const int chunk  = j & 1;             // c2-chunk: [0,16) or [16,32)
    const int rem0   = (j >> 1) * 4;      // 0..796
    const int c2base = chunk * 16;

    const float cw = colw[0];
    const float pw = posw[0];
    const float* __restrict__ in_b  = input + b * (CC * LL);
    float* __restrict__       out_b = out   + b * (CC * LL);

    // ---- stage cd for this block's 256 l2 values, coalesced + nontemporal ----
    {
        const int cd_base = b * (LL * KK2);
        #pragma unroll
        for (int jld = 0; jld < 25; ++jld) {
            int flat = t + 256 * jld;            // [0, 6400)
            int ci   = flat / 100;               // ii 0..63
            int pos  = flat - ci * 100;          // (rem-rem0)*25 + k2
            int gidx = cd_base + (rem0 + 800 * ci) * KK2 + pos;
            gidx = min(gidx, CDTOT - 1);         // clamp OOB tail (values unused)
            smem[ci * 101 + pos] = __builtin_nontemporal_load(&cd[gidx]);
        }
    }
    __syncthreads();

    // ---- per-thread setup ----
    const int remU = __builtin_amdgcn_readfirstlane(rem0 + w);  // wave-uniform
    const int ii   = lane;

    float Wt[KK2];   // per-lane weight, x-mask folded in (fp32)
    int   A0u[KK2];  // WAVE-UNIFORM base: c*LL + 224*dy + dx + e0  (-> SGPRs)
    const float POS[KK2] = {8,5,4,5,8, 5,2,1,2,5, 4,1,0,1,4, 5,2,1,2,5, 8,5,4,5,8};

    #pragma unroll
    for (int k2 = 0; k2 < KK2; ++k2) {
        int t1 = 576 * k2 + remU;       // all scalar:
        int q0 = t1 / 800;
        int r  = t1 - q0 * 800;
        int c  = r / 25;
        int s  = r - c * 25;
        int dy = s / 5 - 2;
        int dx = s % 5 - 2;
        int e0 = 62 * k2 + q0;          // <= 1506
        A0u[k2] = c * LL + 224 * dy + dx + e0;
        int u  = e0 + ii;               // vector: +lane
        int ys = u / 224;               // [0,7]
        int xs = u - ys * 224;
        int xm = xs + dx;
        bool xok = (unsigned)xm < 224u;
        float wgt = fmaf(smem[ii * 101 + w * 25 + k2], cw, POS[k2] * pw);
        Wt[k2] = xok ? wgt : 0.0f;      // x-mask folded into weight
    }
    __syncthreads();   // smem reused as exchange buffer from here

    // mapping B (contiguous-l2) constants for coalesced iv-load / store
    const int remB = t & 3;
    const int iiB  = t >> 2;
    const int l2B  = rem0 + remB + 800 * iiB;
    const bool okB = l2B < LL;
    const int idxB = min(l2B, LL - 1);

    // ---- main loop: 2 groups of 8 channels ----
    #pragma unroll 1
    for (int gg = 0; gg < 2; ++gg) {
        float acc[8], iv[8];
        #pragma unroll
        for (int g = 0; g < 8; ++g) {
            acc[g] = 0.0f;
            iv[g]  = in_b[(c2base + gg * 8 + g) * LL + idxB];  // coalesced, overlaps gathers
        }

        // interior gathers: uniform base + lane offset -> saddr loads
        #pragma unroll
        for (int k2 = 0; k2 < KK2; ++k2) {
            const float wv = Wt[k2];
            #pragma unroll
            for (int g = 0; g < 8; ++g) {
                int c2  = c2base + gg * 8 + g;
                int c2e = min(max(c2, 1), 30);   // special slots: dummy interior read
                const float* bp = in_b + (A0u[k2] + 1568 * c2e);  // wave-uniform ptr
                acc[g] = fmaf(bp[ii], wv, acc[g]);
            }
        }

        // special channels c2=0 / c2=31: clamped + y-masked pass, OVERWRITES acc
        const bool sp_here = (chunk == 0) ? (gg == 0) : (gg == 1);
        if (sp_here) {
            const bool sp0 = (chunk == 0);
            float a = 0.0f;
            #pragma unroll
            for (int k2 = 0; k2 < KK2; ++k2) {
                int t1 = 576 * k2 + remU;
                int q0 = t1 / 800;
                int r  = t1 - q0 * 800;
                int c  = r / 25;
                int s  = r - c * 25;
                int dy = s / 5 - 2;
                int dx = s % 5 - 2;
                int u  = 62 * k2 + q0 + ii;
                int ys = u / 224;
                int xs = u - ys * 224;
                int xc = min(max(xs + dx, 0), 223);
                int yy = ys + dy;                     // [-2, 9]
                int yb = sp0 ? max(yy, 0) : (217 + min(yy, 6));
                bool ok = sp0 ? (yy >= 0) : (yy <= 6);
                float v = in_b[c * LL + yb * 224 + xc];
                a = fmaf(ok ? v : 0.0f, Wt[k2], a);
            }
            if (sp0) acc[0] = a; else acc[7] = a;
        }

        // exchange to mapping B; strides 320/80 -> max 2-way LDS access (free)
        float* sbuf = smem + gg * 2560;
        #pragma unroll
        for (int g = 0; g < 8; ++g)
            sbuf[g * 320 + w * 80 + lane] = acc[g];
        __syncthreads();
        #pragma unroll
        for (int g = 0; g < 8; ++g) {
            float S = sbuf[g * 320 + remB * 80 + iiB];
            if (okB) out_b[(c2base + gg * 8 + g) * LL + idxB] = S * iv[g];  // plain store
        }
        // no trailing barrier: gg=1 uses a disjoint sbuf region
    }
}

extern "C" void kernel_launch(void* const* d_in, const int* in_sizes, int n_in,
                              void* d_out, int out_size, void* d_ws, size_t ws_size,
                              hipStream_t stream) {
    const float* input = (const float*)d_in[0];
    const float* cdist = (const float*)d_in[1];
    const float* cwp   = (const float*)d_in[2];
    const float* pwp   = (const float*)d_in[3];
    float* o = (float*)d_out;

    dim3 grid(1600);   // 4 b x 2 chunks x 200 rem0-tiles, XCD-pinned in-kernel
    dim3 block(256);
    hipLaunchKernelGGL(conv_local_kernel, grid, block, 0, stream,
                       input, cdist, cwp, pwp, o);
}